// Round 2
// baseline (269.304 us; speedup 1.0000x reference)
//
#include <hip/hip_runtime.h>
#include <math.h>

// ---------------------------------------------------------------------------
// PatchEmbedding: gather 9x9x3 patches from frames, x@W1+b1 -> GELU -> @W2+b2
// B=4, T=16, C=3, H=W=256, N=8192, patch_dim=243, EMBED=768
// Inputs/outputs are fp32 (reference dtypes); t_src is int32.
// Internally: convert to bf16, run MFMA bf16 GEMMs (no fp32 MFMA on CDNA4),
// store fp32 output. Tolerance is 2% of max|ref| -> bf16-grade, ample.
// ---------------------------------------------------------------------------

typedef __attribute__((ext_vector_type(8))) short short8;
typedef __attribute__((ext_vector_type(4))) float floatx4;

#define M_ROWS 32768      // B*N = 4*8192
#define KPAD   256        // patch_dim 243 padded to 256
#define EMB    768

__device__ __forceinline__ unsigned short f2bf(float f) {
    union { float f; unsigned int i; } w;
    w.f = f;
    unsigned int x = w.i;
    x += 0x7fffu + ((x >> 16) & 1u);   // round-to-nearest-even
    return (unsigned short)(x >> 16);
}

// --------------------------- prep: W1 (243x768 f32) -> W1T (768x256 bf16, zero-pad)
__global__ void k_transpose_w1(const float* __restrict__ W1,
                               unsigned short* __restrict__ W1T) {
    int idx = blockIdx.x * 256 + threadIdx.x;   // 768*256 total
    int n = idx >> 8;        // 0..767
    int k = idx & 255;       // 0..255
    W1T[idx] = (k < 243) ? f2bf(W1[k * EMB + n]) : (unsigned short)0;
}

// --------------------------- prep: W2 (768x768 f32) -> W2T (768x768 bf16)
__global__ void k_transpose_w2(const float* __restrict__ W2,
                               unsigned short* __restrict__ W2T) {
    int idx = blockIdx.x * 256 + threadIdx.x;   // 768*768 total
    int n = idx / EMB;
    int k = idx - n * EMB;
    W2T[idx] = f2bf(W2[k * EMB + n]);
}

// --------------------------- gather patches -> X (32768 x 256 bf16, padded)
// one wave per row; element e = i*27 + j*3 + c  (i=patch row, j=patch col, c=chan)
__global__ void k_gather(const float* __restrict__ frames,
                         const float* __restrict__ coords,
                         const int* __restrict__ t_src,
                         unsigned short* __restrict__ X) {
    int row  = blockIdx.x * 4 + (threadIdx.x >> 6);   // 0..32767
    int lane = threadIdx.x & 63;
    int b = row >> 13;                                 // /8192

    float cu = coords[row * 2 + 0];
    float cv = coords[row * 2 + 1];
    int u = (int)(cu * 255.0f);   // exact fp32 math, matches reference
    int v = (int)(cv * 255.0f);
    int t = t_src[row];

    const float* fb = frames + (size_t)(b * 16 + t) * (3 * 256 * 256);
    unsigned short* xr = X + (size_t)row * KPAD;

#pragma unroll
    for (int it = 0; it < 4; ++it) {
        int e = lane + it * 64;
        unsigned short val = 0;
        if (e < 243) {
            int c  = e % 3;
            int ij = e / 3;
            int j  = ij % 9;
            int i  = ij / 9;
            int y = v + i - 4; y = (y < 0) ? 0 : (y > 255 ? 255 : y);
            int x = u + j - 4; x = (x < 0) ? 0 : (x > 255 ? 255 : x);
            val = f2bf(fb[(size_t)c * 65536 + y * 256 + x]);
        }
        xr[e] = val;
    }
}

// --------------------------- MFMA GEMM: C(MxEMB) = act(A(MxK) * BT(EMBxK)^T + bias)
// 128x128 tile per 256-thread block (4 waves, each 64x64), BK=64.
// LDS leading dim 72 elems (144B): 16B-aligned b128 access, conflict-light.
template <int K, bool GELU, bool OUT_F32>
__global__ __launch_bounds__(256)
void k_gemm(const unsigned short* __restrict__ A,
            const unsigned short* __restrict__ BT,
            const float* __restrict__ bias,
            void* __restrict__ Cv) {
    const int BK = 64, LDK = 72;
    __shared__ unsigned short As[128 * LDK];
    __shared__ unsigned short Bs[128 * LDK];

    int tid  = threadIdx.x;
    int wave = tid >> 6;
    int lane = tid & 63;
    int wm = (wave >> 1) * 64;      // wave row offset in tile
    int wn = (wave & 1) * 64;       // wave col offset in tile
    int lm = lane & 15;
    int lq = lane >> 4;

    int m0 = blockIdx.x * 128;
    int n0 = blockIdx.y * 128;

    floatx4 acc[4][4];
#pragma unroll
    for (int i = 0; i < 4; ++i)
#pragma unroll
        for (int j = 0; j < 4; ++j)
            acc[i][j] = (floatx4){0.f, 0.f, 0.f, 0.f};

    const unsigned short* Ag = A  + (size_t)m0 * K;
    const unsigned short* Bg = BT + (size_t)n0 * K;

    for (int k0 = 0; k0 < K; k0 += BK) {
        // stage A-tile and B-tile (each 128x64 bf16 = 16 KB): 1024 16B-chunks each
#pragma unroll
        for (int i = 0; i < 4; ++i) {
            int chunk = tid + i * 256;        // 0..1023
            int r  = chunk >> 3;              // 0..127
            int kc = (chunk & 7) << 3;        // 0,8,...,56
            short8 va = *(const short8*)(Ag + (size_t)r * K + k0 + kc);
            *(short8*)(&As[r * LDK + kc]) = va;
            short8 vb = *(const short8*)(Bg + (size_t)r * K + k0 + kc);
            *(short8*)(&Bs[r * LDK + kc]) = vb;
        }
        __syncthreads();

#pragma unroll
        for (int ks = 0; ks < 2; ++ks) {      // two K=32 steps per BK=64 tile
            short8 af[4], bf[4];
#pragma unroll
            for (int mi = 0; mi < 4; ++mi)
                af[mi] = *(const short8*)(&As[(wm + mi * 16 + lm) * LDK + ks * 32 + lq * 8]);
#pragma unroll
            for (int ni = 0; ni < 4; ++ni)
                bf[ni] = *(const short8*)(&Bs[(wn + ni * 16 + lm) * LDK + ks * 32 + lq * 8]);
#pragma unroll
            for (int mi = 0; mi < 4; ++mi)
#pragma unroll
                for (int ni = 0; ni < 4; ++ni)
                    acc[mi][ni] = __builtin_amdgcn_mfma_f32_16x16x32_bf16(
                        af[mi], bf[ni], acc[mi][ni], 0, 0, 0);
        }
        __syncthreads();
    }

    // epilogue: D[row][col], row = lq*4 + r, col = lm within each 16x16 tile
#pragma unroll
    for (int ni = 0; ni < 4; ++ni) {
        int col = n0 + wn + ni * 16 + lm;
        float bs = bias[col];
#pragma unroll
        for (int mi = 0; mi < 4; ++mi) {
            int rowb = m0 + wm + mi * 16 + lq * 4;
#pragma unroll
            for (int r = 0; r < 4; ++r) {
                float x = acc[mi][ni][r] + bs;
                if (GELU)
                    x = 0.5f * x * (1.0f + erff(x * 0.70710678118f));
                size_t idx = (size_t)(rowb + r) * EMB + col;
                if (OUT_F32)
                    ((float*)Cv)[idx] = x;
                else
                    ((unsigned short*)Cv)[idx] = f2bf(x);
            }
        }
    }
}

// ---------------------------------------------------------------------------
extern "C" void kernel_launch(void* const* d_in, const int* in_sizes, int n_in,
                              void* d_out, int out_size, void* d_ws, size_t ws_size,
                              hipStream_t stream) {
    const float* frames = (const float*)d_in[0];
    const float* coords = (const float*)d_in[1];
    const int*   t_src  = (const int*)d_in[2];
    const float* W1     = (const float*)d_in[3];
    const float* b1     = (const float*)d_in[4];
    const float* W2     = (const float*)d_in[5];
    const float* b2     = (const float*)d_in[6];
    float* out = (float*)d_out;

    char* ws = (char*)d_ws;
    // workspace layout (all 16B+ aligned):
    //   X   : 32768*256*2  = 16,777,216 B   (bf16)
    //   Hbuf: 32768*768*2  = 50,331,648 B   (bf16)
    //   W1T : 768*256*2    =    393,216 B   (bf16)
    //   W2T : 768*768*2    =  1,179,648 B   (bf16)
    unsigned short* X    = (unsigned short*)(ws);
    unsigned short* Hbuf = (unsigned short*)(ws + 16777216);
    unsigned short* W1T  = (unsigned short*)(ws + 16777216 + 50331648);
    unsigned short* W2T  = (unsigned short*)(ws + 16777216 + 50331648 + 393216);

    // prep transposes (tiny)
    k_transpose_w1<<<768, 256, 0, stream>>>(W1, W1T);
    k_transpose_w2<<<2304, 256, 0, stream>>>(W2, W2T);

    // gather patches (one wave per row)
    k_gather<<<M_ROWS / 4, 256, 0, stream>>>(frames, coords, t_src, X);

    // GEMM1: H = gelu(X @ W1 + b1)   (K = 256 padded), bf16 out
    k_gemm<KPAD, true, false><<<dim3(M_ROWS / 128, EMB / 128), 256, 0, stream>>>(X, W1T, b1, Hbuf);

    // GEMM2: out = H @ W2 + b2       (K = 768), fp32 out
    k_gemm<EMB, false, true><<<dim3(M_ROWS / 128, EMB / 128), 256, 0, stream>>>(Hbuf, W2T, b2, out);
}

// Round 3
// 244.454 us; speedup vs baseline: 1.1017x; 1.1017x over previous
//
#include <hip/hip_runtime.h>
#include <math.h>

// ---------------------------------------------------------------------------
// PatchEmbedding: gather 9x9x3 patches from frames, x@W1+b1 -> GELU -> @W2+b2
// B=4, T=16, C=3, H=W=256, N=8192, patch_dim=243, EMBED=768
// Inputs/outputs fp32; t_src int32. Internally bf16 MFMA (no fp32 MFMA on CDNA4).
//
// K-order trick: X and W1T both use the permuted order k' = c*81 + i*9 + j
// (channel-major) so the gather reads are x-contiguous per 9-lane group.
// The GEMM only needs X[:,k'] and W1T[:,k'] consistent — which they are.
// ---------------------------------------------------------------------------

typedef __attribute__((ext_vector_type(8))) short short8;
typedef __attribute__((ext_vector_type(4))) float floatx4;

#define M_ROWS 32768      // B*N = 4*8192
#define KPAD   256        // patch_dim 243 padded to 256
#define EMB    768

typedef __attribute__((address_space(1))) const void g_void;
typedef __attribute__((address_space(3))) void l_void;

__device__ __forceinline__ unsigned short f2bf(float f) {
    union { float f; unsigned int i; } w;
    w.f = f;
    unsigned int x = w.i;
    x += 0x7fffu + ((x >> 16) & 1u);   // round-to-nearest-even
    return (unsigned short)(x >> 16);
}

// ---- prep: W1 (243x768 f32) -> W1T (768x256 bf16, zero-pad, permuted k') ----
__global__ void k_transpose_w1(const float* __restrict__ W1,
                               unsigned short* __restrict__ W1T) {
    int idx = blockIdx.x * 256 + threadIdx.x;   // 768*256 total
    int n  = idx >> 8;        // 0..767
    int kp = idx & 255;       // permuted k': c*81 + i*9 + j
    unsigned short v = 0;
    if (kp < 243) {
        int c = kp / 81;
        int r = kp - c * 81;
        int i = r / 9;
        int j = r - i * 9;
        int e = i * 27 + j * 3 + c;   // reference order
        v = f2bf(W1[e * EMB + n]);
    }
    W1T[idx] = v;
}

// ---- prep: W2 (768x768 f32) -> W2T (768x768 bf16), LDS-tiled transpose ----
__global__ void k_transpose_w2(const float* __restrict__ W2,
                               unsigned short* __restrict__ W2T) {
    __shared__ float tile[32][33];
    int tx = threadIdx.x & 31, ty = threadIdx.x >> 5;   // 32 x 8
    int k0 = blockIdx.x * 32, n0 = blockIdx.y * 32;
#pragma unroll
    for (int i = 0; i < 4; ++i)
        tile[ty + i * 8][tx] = W2[(size_t)(k0 + ty + i * 8) * EMB + n0 + tx];
    __syncthreads();
#pragma unroll
    for (int i = 0; i < 4; ++i)
        W2T[(size_t)(n0 + ty + i * 8) * EMB + k0 + tx] = f2bf(tile[tx][ty + i * 8]);
}

// ---- gather patches -> X (32768 x 256 bf16), channel-major order k' --------
__global__ void k_gather(const float* __restrict__ frames,
                         const float* __restrict__ coords,
                         const int* __restrict__ t_src,
                         unsigned short* __restrict__ X) {
    int row  = blockIdx.x * 4 + (threadIdx.x >> 6);   // 0..32767
    int lane = threadIdx.x & 63;
    int b = row >> 13;                                 // /8192

    float cu = coords[row * 2 + 0];
    float cv = coords[row * 2 + 1];
    int u = (int)(cu * 255.0f);   // exact fp32 math, matches reference
    int v = (int)(cv * 255.0f);
    int t = t_src[row];

    const float* fb = frames + (size_t)(b * 16 + t) * (3 * 256 * 256);
    unsigned short* xr = X + (size_t)row * KPAD;

#pragma unroll
    for (int it = 0; it < 4; ++it) {
        int kp = lane + it * 64;            // permuted index c*81 + i*9 + j
        unsigned short val = 0;
        if (kp < 243) {
            int c = kp / 81;
            int r = kp - c * 81;
            int i = r / 9;
            int j = r - i * 9;
            int y = v + i - 4; y = (y < 0) ? 0 : (y > 255 ? 255 : y);
            int x = u + j - 4; x = (x < 0) ? 0 : (x > 255 ? 255 : x);
            val = f2bf(fb[(size_t)c * 65536 + y * 256 + x]);
        }
        xr[kp] = val;
    }
}

// ---- MFMA GEMM: C(MxEMB) = act(A(MxK) @ BT(EMBxK)^T + bias) ---------------
// 128x128 tile / 256-thread block (4 waves, each 64x64 via 4x4 16x16x32 MFMA).
// Staging: global_load_lds width=16 (m97 rung). LDS is unpadded 128x64 with an
// XOR swizzle: data for logical 16B-slot s of row r lives at slot s^(r&7).
// Legal because global_load_lds's LDS side is lane-ordered but the global
// source address is per-lane free. Fragment b128 reads become 2-way (free).
template <int K, bool GELU, bool OUT_F32>
__global__ __launch_bounds__(256, 3)
void k_gemm(const unsigned short* __restrict__ A,
            const unsigned short* __restrict__ BT,
            const float* __restrict__ bias,
            void* __restrict__ Cv) {
    __shared__ unsigned short As[128 * 64];
    __shared__ unsigned short Bs[128 * 64];

    int tid  = threadIdx.x;
    int wave = tid >> 6;
    int lane = tid & 63;
    int wm = (wave >> 1) * 64;      // wave row offset in tile
    int wn = (wave & 1) * 64;       // wave col offset in tile
    int lm = lane & 15;
    int lq = lane >> 4;

    int m0 = blockIdx.x * 128;
    int n0 = blockIdx.y * 128;

    floatx4 acc[4][4];
#pragma unroll
    for (int i = 0; i < 4; ++i)
#pragma unroll
        for (int j = 0; j < 4; ++j)
            acc[i][j] = (floatx4){0.f, 0.f, 0.f, 0.f};

    const unsigned short* Ag = A  + (size_t)m0 * K;
    const unsigned short* Bg = BT + (size_t)n0 * K;

    // staging geometry: chunk = wave*4+i covers rows [chunk*8, chunk*8+8),
    // lane -> row chunk*8 + (lane>>3), physical 16B slot lane&7.
    int rl    = lane >> 3;
    int pslot = lane & 7;

    for (int k0 = 0; k0 < K; k0 += 64) {
#pragma unroll
        for (int i = 0; i < 4; ++i) {
            int chunk = wave * 4 + i;            // 0..15
            int r     = chunk * 8 + rl;          // 0..127
            int lslot = pslot ^ (r & 7);         // logical slot stored here
            const unsigned short* ga = Ag + (size_t)r * K + k0 + (lslot << 3);
            const unsigned short* gb = Bg + (size_t)r * K + k0 + (lslot << 3);
            __builtin_amdgcn_global_load_lds((g_void*)ga, (l_void*)(As + chunk * 512), 16, 0, 0);
            __builtin_amdgcn_global_load_lds((g_void*)gb, (l_void*)(Bs + chunk * 512), 16, 0, 0);
        }
        __syncthreads();

#pragma unroll
        for (int ks = 0; ks < 2; ++ks) {         // two K=32 steps per BK=64
            short8 af[4], bfr[4];
#pragma unroll
            for (int mi = 0; mi < 4; ++mi) {
                int row = wm + mi * 16 + lm;
                int ps  = ((ks << 2) + lq) ^ (row & 7);
                af[mi] = *(const short8*)(As + row * 64 + (ps << 3));
            }
#pragma unroll
            for (int ni = 0; ni < 4; ++ni) {
                int row = wn + ni * 16 + lm;
                int ps  = ((ks << 2) + lq) ^ (row & 7);
                bfr[ni] = *(const short8*)(Bs + row * 64 + (ps << 3));
            }
#pragma unroll
            for (int mi = 0; mi < 4; ++mi)
#pragma unroll
                for (int ni = 0; ni < 4; ++ni)
                    acc[mi][ni] = __builtin_amdgcn_mfma_f32_16x16x32_bf16(
                        af[mi], bfr[ni], acc[mi][ni], 0, 0, 0);
        }
        __syncthreads();
    }

    // epilogue: D[row][col], row = lq*4 + r, col = lm within each 16x16 tile
#pragma unroll
    for (int ni = 0; ni < 4; ++ni) {
        int col = n0 + wn + ni * 16 + lm;
        float bs = bias[col];
#pragma unroll
        for (int mi = 0; mi < 4; ++mi) {
            int rowb = m0 + wm + mi * 16 + lq * 4;
#pragma unroll
            for (int r = 0; r < 4; ++r) {
                float x = acc[mi][ni][r] + bs;
                if (GELU)
                    x = 0.5f * x * (1.0f + erff(x * 0.70710678118f));
                size_t idx = (size_t)(rowb + r) * EMB + col;
                if (OUT_F32)
                    ((float*)Cv)[idx] = x;
                else
                    ((unsigned short*)Cv)[idx] = f2bf(x);
            }
        }
    }
}

// ---------------------------------------------------------------------------
extern "C" void kernel_launch(void* const* d_in, const int* in_sizes, int n_in,
                              void* d_out, int out_size, void* d_ws, size_t ws_size,
                              hipStream_t stream) {
    const float* frames = (const float*)d_in[0];
    const float* coords = (const float*)d_in[1];
    const int*   t_src  = (const int*)d_in[2];
    const float* W1     = (const float*)d_in[3];
    const float* b1     = (const float*)d_in[4];
    const float* W2     = (const float*)d_in[5];
    const float* b2     = (const float*)d_in[6];
    float* out = (float*)d_out;

    char* ws = (char*)d_ws;
    // workspace layout:
    //   X   : 32768*256*2  = 16,777,216 B   (bf16, permuted k')
    //   Hbuf: 32768*768*2  = 50,331,648 B   (bf16)
    //   W1T : 768*256*2    =    393,216 B   (bf16, permuted k')
    //   W2T : 768*768*2    =  1,179,648 B   (bf16)
    unsigned short* X    = (unsigned short*)(ws);
    unsigned short* Hbuf = (unsigned short*)(ws + 16777216);
    unsigned short* W1T  = (unsigned short*)(ws + 16777216 + 50331648);
    unsigned short* W2T  = (unsigned short*)(ws + 16777216 + 50331648 + 393216);

    // prep transposes (tiny)
    k_transpose_w1<<<768, 256, 0, stream>>>(W1, W1T);
    k_transpose_w2<<<dim3(24, 24), 256, 0, stream>>>(W2, W2T);

    // gather patches (one wave per row, channel-major element order)
    k_gather<<<M_ROWS / 4, 256, 0, stream>>>(frames, coords, t_src, X);

    // GEMM1: H = gelu(X @ W1 + b1)   (K = 256 padded), bf16 out
    k_gemm<KPAD, true, false><<<dim3(M_ROWS / 128, EMB / 128), 256, 0, stream>>>(X, W1T, b1, Hbuf);

    // GEMM2: out = H @ W2 + b2       (K = 768), fp32 out
    k_gemm<EMB, false, true><<<dim3(M_ROWS / 128, EMB / 128), 256, 0, stream>>>(Hbuf, W2T, b2, out);
}